// Round 2
// baseline (82.507 us; speedup 1.0000x reference)
//
#include <hip/hip_runtime.h>
#include <math.h>

#define BATCH  8192
#define KNEI   30
#define LATENT 256
#define NDIST  60   // 2*K

// One block (256 threads, 4 waves) per batch element.
__global__ __launch_bounds__(256) void softnp_dist_kernel(
    const float* __restrict__ z_all,
    const int* __restrict__ knn,       // (N, K) int32 (harness converts int64 -> int32)
    const int* __restrict__ cell,      // (B,)
    const int* __restrict__ neg,       // (B, K)
    float* __restrict__ losses)        // (B,)
{
    const int b    = blockIdx.x;
    const int tid  = threadIdx.x;
    const int wave = tid >> 6;
    const int lane = tid & 63;

    __shared__ float zi[LATENT];
    __shared__ float dist[NDIST + 4];

    const int ci = cell[b];

    // Stage z_i into LDS (coalesced: 256 threads, 256 floats)
    zi[tid] = z_all[(size_t)ci * LATENT + tid];
    __syncthreads();

    // Each lane's float4 slice of z_i (elements lane*4 .. lane*4+3)
    const float4 zv = *reinterpret_cast<const float4*>(&zi[lane * 4]);

    // 60 distances distributed over 4 waves; each wave reads one full
    // 1024B row coalesced (64 lanes x float4) and shfl-reduces.
    for (int k = wave; k < NDIST; k += 4) {
        int idx;
        if (k < KNEI) idx = knn[(size_t)ci * KNEI + k];
        else          idx = neg[(size_t)b * KNEI + (k - KNEI)];

        const float4 v = reinterpret_cast<const float4*>(z_all + (size_t)idx * LATENT)[lane];
        const float dx = v.x - zv.x;
        const float dy = v.y - zv.y;
        const float dz = v.z - zv.z;
        const float dw = v.w - zv.w;
        float s = dx * dx + dy * dy + dz * dz + dw * dw;

        #pragma unroll
        for (int off = 32; off > 0; off >>= 1)
            s += __shfl_xor(s, off, 64);

        if (lane == 0) dist[k] = sqrtf(s);
    }
    __syncthreads();

    // Wave 0: 60-wide softmax over -dist (TEMPERATURE == 1)
    if (wave == 0) {
        const float sc = (lane < NDIST) ? -dist[lane] : -INFINITY;

        float m = sc;
        #pragma unroll
        for (int off = 32; off > 0; off >>= 1)
            m = fmaxf(m, __shfl_xor(m, off, 64));

        const float e = (lane < NDIST) ? expf(sc - m) : 0.0f;
        float tot = e;
        float top = (lane < KNEI) ? e : 0.0f;
        #pragma unroll
        for (int off = 32; off > 0; off >>= 1) {
            tot += __shfl_xor(tot, off, 64);
            top += __shfl_xor(top, off, 64);
        }

        if (lane == 0)
            losses[b] = -logf(top / tot + 1e-8f);
    }
}

// Deterministic mean over the 8192 per-element losses.
__global__ __launch_bounds__(1024) void softnp_reduce_kernel(
    const float* __restrict__ losses, float* __restrict__ out)
{
    const int tid  = threadIdx.x;
    const int wave = tid >> 6;
    const int lane = tid & 63;

    float s = 0.0f;
    for (int i = tid; i < BATCH; i += 1024)
        s += losses[i];

    #pragma unroll
    for (int off = 32; off > 0; off >>= 1)
        s += __shfl_xor(s, off, 64);

    __shared__ float buf[16];
    if (lane == 0) buf[wave] = s;
    __syncthreads();

    if (tid == 0) {
        float t = 0.0f;
        #pragma unroll
        for (int i = 0; i < 16; ++i) t += buf[i];
        out[0] = t / (float)BATCH;
    }
}

extern "C" void kernel_launch(void* const* d_in, const int* in_sizes, int n_in,
                              void* d_out, int out_size, void* d_ws, size_t ws_size,
                              hipStream_t stream) {
    const float* z_all = (const float*)d_in[0];
    const int*   knn   = (const int*)d_in[1];
    const int*   cell  = (const int*)d_in[2];
    const int*   neg   = (const int*)d_in[3];
    float* out    = (float*)d_out;
    float* losses = (float*)d_ws;   // BATCH floats of scratch

    softnp_dist_kernel<<<BATCH, 256, 0, stream>>>(z_all, knn, cell, neg, losses);
    softnp_reduce_kernel<<<1, 1024, 0, stream>>>(losses, out);
}

// Round 3
// 82.036 us; speedup vs baseline: 1.0057x; 1.0057x over previous
//
#include <hip/hip_runtime.h>
#include <math.h>

#define BATCH  8192
#define KNEI   30
#define LATENT 256
#define NDIST  60            // 2*K
#define ROWS_PER_WAVE 15     // NDIST / 4 waves

// One block (256 threads, 4 waves) per batch element.
__global__ __launch_bounds__(256) void softnp_dist_kernel(
    const float* __restrict__ z_all,
    const int* __restrict__ knn,       // (N, K) int32
    const int* __restrict__ cell,      // (B,)
    const int* __restrict__ neg,       // (B, K)
    float* __restrict__ losses)        // (B,)
{
    const int b    = blockIdx.x;
    const int tid  = threadIdx.x;
    const int wave = tid >> 6;
    const int lane = tid & 63;

    __shared__ float dist[NDIST + 4];

    const int ci = cell[b];

    // Each lane's float4 slice of z_i; all 4 waves read the same 1 KB row
    // (L1/L2 broadcast) - no LDS round trip, no extra barrier.
    const float4 zv = reinterpret_cast<const float4*>(z_all + (size_t)ci * LATENT)[lane];

    // ---- load all 15 wave-uniform indices ----
    int idx[ROWS_PER_WAVE];
    #pragma unroll
    for (int j = 0; j < ROWS_PER_WAVE; ++j) {
        const int k = wave + 4 * j;
        idx[j] = (k < KNEI) ? knn[(size_t)ci * KNEI + k]
                            : neg[(size_t)b * KNEI + (k - KNEI)];
    }

    // ---- issue all 15 gathers (1 KB coalesced each) up-front ----
    float4 v[ROWS_PER_WAVE];
    #pragma unroll
    for (int j = 0; j < ROWS_PER_WAVE; ++j)
        v[j] = reinterpret_cast<const float4*>(z_all + (size_t)idx[j] * LATENT)[lane];

    // ---- per-lane partial squared distances (independent FMA chains) ----
    float s[ROWS_PER_WAVE];
    #pragma unroll
    for (int j = 0; j < ROWS_PER_WAVE; ++j) {
        const float dx = v[j].x - zv.x;
        const float dy = v[j].y - zv.y;
        const float dz = v[j].z - zv.z;
        const float dw = v[j].w - zv.w;
        s[j] = dx * dx + dy * dy + dz * dz + dw * dw;
    }

    // ---- batched wave reduction: 15 independent values pipeline through
    //      each shuffle stage instead of 15 serial 6-deep chains ----
    #pragma unroll
    for (int off = 32; off > 0; off >>= 1) {
        #pragma unroll
        for (int j = 0; j < ROWS_PER_WAVE; ++j)
            s[j] += __shfl_xor(s[j], off, 64);
    }

    if (lane == 0) {
        #pragma unroll
        for (int j = 0; j < ROWS_PER_WAVE; ++j)
            dist[wave + 4 * j] = sqrtf(s[j]);
    }
    __syncthreads();

    // ---- wave 0: 60-wide softmax over -dist (TEMPERATURE == 1) ----
    if (wave == 0) {
        const float sc = (lane < NDIST) ? -dist[lane] : -INFINITY;

        float m = sc;
        #pragma unroll
        for (int off = 32; off > 0; off >>= 1)
            m = fmaxf(m, __shfl_xor(m, off, 64));

        const float e = (lane < NDIST) ? expf(sc - m) : 0.0f;
        float tot = e;
        float top = (lane < KNEI) ? e : 0.0f;
        #pragma unroll
        for (int off = 32; off > 0; off >>= 1) {
            tot += __shfl_xor(tot, off, 64);
            top += __shfl_xor(top, off, 64);
        }

        if (lane == 0)
            losses[b] = -logf(top / tot + 1e-8f);
    }
}

// Deterministic mean over the 8192 per-element losses.
__global__ __launch_bounds__(1024) void softnp_reduce_kernel(
    const float* __restrict__ losses, float* __restrict__ out)
{
    const int tid  = threadIdx.x;
    const int wave = tid >> 6;
    const int lane = tid & 63;

    float s = 0.0f;
    for (int i = tid; i < BATCH; i += 1024)
        s += losses[i];

    #pragma unroll
    for (int off = 32; off > 0; off >>= 1)
        s += __shfl_xor(s, off, 64);

    __shared__ float buf[16];
    if (lane == 0) buf[wave] = s;
    __syncthreads();

    if (tid == 0) {
        float t = 0.0f;
        #pragma unroll
        for (int i = 0; i < 16; ++i) t += buf[i];
        out[0] = t / (float)BATCH;
    }
}

extern "C" void kernel_launch(void* const* d_in, const int* in_sizes, int n_in,
                              void* d_out, int out_size, void* d_ws, size_t ws_size,
                              hipStream_t stream) {
    const float* z_all = (const float*)d_in[0];
    const int*   knn   = (const int*)d_in[1];
    const int*   cell  = (const int*)d_in[2];
    const int*   neg   = (const int*)d_in[3];
    float* out    = (float*)d_out;
    float* losses = (float*)d_ws;   // BATCH floats of scratch

    softnp_dist_kernel<<<BATCH, 256, 0, stream>>>(z_all, knn, cell, neg, losses);
    softnp_reduce_kernel<<<1, 1024, 0, stream>>>(losses, out);
}